// Round 8
// baseline (160.323 us; speedup 1.0000x reference)
//
#include <hip/hip_runtime.h>
#include <hip/hip_bf16.h>

#define B_  16
#define NQ_ 512
#define NK_ 1024
#define CQ_ 128
#define H_  8
#define D_  64
#define HD_ 512   // H*D

typedef __attribute__((ext_vector_type(8))) short short8;
typedef __attribute__((ext_vector_type(4))) float floatx4;

__device__ __forceinline__ short f2bf(float f) {
    union { float f; unsigned u; } x; x.f = f;
    unsigned r = (x.u + 0x7fffu + ((x.u >> 16) & 1u)) >> 16;  // RNE
    return (short)r;
}
__device__ __forceinline__ int f2bf_pk(float a, float b) {   // packed RNE (v_cvt_pk_bf16_f32)
    __hip_bfloat162 h = __float22bfloat162_rn(make_float2(a, b));
    int r; __builtin_memcpy(&r, &h, 4); return r;
}
__device__ __forceinline__ short8 pack8(float4 a, float4 b) {
    union { int4 i; short8 s; } u;
    u.i = make_int4(f2bf_pk(a.x, a.y), f2bf_pk(a.z, a.w),
                    f2bf_pk(b.x, b.y), f2bf_pk(b.z, b.w));
    return u.s;
}
__device__ __forceinline__ int2 packi2(floatx4 a) {
    return make_int2(f2bf_pk(a[0], a[1]), f2bf_pk(a[2], a[3]));
}

// ---- Stage 0 (prep): W[128][512] fp32 -> Wt[512][128] bf16 (x3), qscale
// folded into wqt and bqs so the fused kernel works in exp2 domain directly.
__global__ void prep_kernel(const float* __restrict__ W0, const float* __restrict__ W1,
                            const float* __restrict__ W2, short* __restrict__ T0,
                            short* __restrict__ T1, short* __restrict__ T2,
                            const float* __restrict__ bq, float* __restrict__ bqs,
                            float qscale) {
    int gi = blockIdx.x * blockDim.x + threadIdx.x;   // 0..197119
    if (gi < 196608) {
        int sel = gi >> 16;
        int idx = gi & 65535;                         // = n*128 + k
        const float* W = sel == 0 ? W0 : (sel == 1 ? W1 : W2);
        short* T = sel == 0 ? T0 : (sel == 1 ? T1 : T2);
        float s = sel == 0 ? qscale : 1.0f;
        int n = idx >> 7, k = idx & 127;
        T[idx] = f2bf(W[k * HD_ + n] * s);
        return;
    }
    int j = gi - 196608;
    if (j < HD_) bqs[j] = bq[j] * qscale;
}

// ---- Fused projection + flash attention ----
// grid 256 = (qhalf in bit7, bh in bits0..6), 512 threads (8 waves).
// Per block: project Q for its 256 q-rows once (in-register via LDS round
// trip); then per 64-key chunk, waves 0-3 project K and waves 4-7 project V
// into double-buffered LDS (one barrier/chunk), and all 8 waves run S^T
// attention (fixed-max exp2 softmax, operand-swapped PV -> O^T epilogue).
__global__ __launch_bounds__(512, 2) void fused_kernel(
    const float* __restrict__ query, const float* __restrict__ key_,
    const float* __restrict__ cmask,
    const short* __restrict__ wqt, const short* __restrict__ wkt,
    const short* __restrict__ wvt,
    const float* __restrict__ bqs, const float* __restrict__ bk,
    const float* __restrict__ bv, float* __restrict__ out)
{
    __shared__ __align__(16) short ksh[2][64 * 72];   // [key][d]
    __shared__ __align__(16) short vsh[2][64 * 72];   // [d][key]
    __shared__ __align__(16) short psh[256 * 72];     // phase A: [q][d]; main: [q][key]

    const int tid = threadIdx.x;
    const int w = tid >> 6, lane = tid & 63;
    const int l15 = lane & 15, quad = lane >> 4;

    const int bx     = blockIdx.x;
    const int bh_i   = bx & 127;          // bh%8 tracks dispatch%8 -> XCD locality
    const int qhalf  = bx >> 7;
    const int h      = bh_i & 7;
    const int b      = bh_i >> 3;

    const float* xkey = key_ + (size_t)b * NK_ * CQ_;
    const float* mk   = cmask + (size_t)b * NK_;

    const short* Wkv = (w < 4) ? wkt : wvt;
    const int nt = w & 3;                  // proj-role tile index

    // --- Phase A: Q projection (swapped: D[m=d][n=q]) ---
    short8 qa[2][2];
    {
        short8 waf[4][4];
        #pragma unroll
        for (int dt = 0; dt < 4; ++dt)
            #pragma unroll
            for (int kt = 0; kt < 4; ++kt)
                waf[dt][kt] = *(const short8*)(wqt + (size_t)(h * 64 + dt * 16 + l15) * CQ_ + kt * 32 + quad * 8);
        const int qr0 = qhalf * 256 + w * 32;
        #pragma unroll
        for (int g = 0; g < 2; ++g) {
            const float* qrow = query + ((size_t)b * NQ_ + qr0 + g * 16 + l15) * CQ_;
            short8 bqf[4];
            #pragma unroll
            for (int kt = 0; kt < 4; ++kt)
                bqf[kt] = pack8(*(const float4*)(qrow + kt * 32 + quad * 8),
                                *(const float4*)(qrow + kt * 32 + quad * 8 + 4));
            const int prow = (w * 32 + g * 16 + l15) * 72;
            #pragma unroll
            for (int dt = 0; dt < 4; ++dt) {
                float4 bi = *(const float4*)(bqs + h * 64 + dt * 16 + quad * 4);
                floatx4 a = {bi.x, bi.y, bi.z, bi.w};
                #pragma unroll
                for (int kt = 0; kt < 4; ++kt)
                    a = __builtin_amdgcn_mfma_f32_16x16x32_bf16(waf[dt][kt], bqf[kt], a, 0, 0, 0);
                *(int2*)&psh[prow + dt * 16 + quad * 4] = packi2(a);
            }
            qa[g][0] = *(const short8*)&psh[prow + quad * 8];
            qa[g][1] = *(const short8*)&psh[prow + 32 + quad * 8];
        }
    }

    float l_lane[2] = {0.f, 0.f};
    floatx4 o_acc[2][4];
    #pragma unroll
    for (int g = 0; g < 2; ++g)
        #pragma unroll
        for (int dt = 0; dt < 4; ++dt) o_acc[g][dt] = (floatx4){0.f, 0.f, 0.f, 0.f};

    // --- K/V chunk projection (into buf) ---
    auto proj_mfma_write = [&](const short8 xf[4], const short8 wf[4][4], int bufi) {
        if (w < 4) {       // K: D[m=d][n=key], pack 4 d per lane -> ksh[key][d]
            #pragma unroll
            for (int dt = 0; dt < 4; ++dt) {
                float4 bi = *(const float4*)(bk + h * 64 + dt * 16 + quad * 4);
                floatx4 a = {bi.x, bi.y, bi.z, bi.w};
                #pragma unroll
                for (int kt = 0; kt < 4; ++kt)
                    a = __builtin_amdgcn_mfma_f32_16x16x32_bf16(wf[dt][kt], xf[kt], a, 0, 0, 0);
                *(int2*)&ksh[bufi][(nt * 16 + l15) * 72 + dt * 16 + quad * 4] = packi2(a);
            }
        } else {           // V: D[m=key][n=d], pack 4 keys per lane -> vsh[d][key]
            #pragma unroll
            for (int dt = 0; dt < 4; ++dt) {
                const float bvv = bv[h * 64 + dt * 16 + l15];
                floatx4 a = {bvv, bvv, bvv, bvv};
                #pragma unroll
                for (int kt = 0; kt < 4; ++kt)
                    a = __builtin_amdgcn_mfma_f32_16x16x32_bf16(xf[kt], wf[dt][kt], a, 0, 0, 0);
                *(int2*)&vsh[bufi][(dt * 16 + l15) * 72 + nt * 16 + quad * 4] = packi2(a);
            }
        }
    };
    auto load_xf = [&](int kbase, short8 xf[4]) {
        const float* krow = xkey + (size_t)(kbase + nt * 16 + l15) * CQ_;
        #pragma unroll
        for (int kt = 0; kt < 4; ++kt)
            xf[kt] = pack8(*(const float4*)(krow + kt * 32 + quad * 8),
                           *(const float4*)(krow + kt * 32 + quad * 8 + 4));
    };
    auto load_wf = [&](short8 wf[4][4]) {
        #pragma unroll
        for (int dt = 0; dt < 4; ++dt)
            #pragma unroll
            for (int kt = 0; kt < 4; ++kt)
                wf[dt][kt] = *(const short8*)(Wkv + (size_t)(h * 64 + dt * 16 + l15) * CQ_ + kt * 32 + quad * 8);
    };

    // prologue: project chunk 0
    {
        short8 xf[4], wf[4][4];
        load_xf(0, xf);
        load_wf(wf);
        proj_mfma_write(xf, wf, 0);
    }
    __syncthreads();

    for (int t = 0; t < 16; ++t) {
        const int cur = t & 1;
        const int kbase = t * 64;

        // issue next chunk's X loads early (land during attn below)
        short8 xf[4];
        if (t < 15) load_xf(kbase + 64, xf);

        // mask for this lane's 16 keys
        float4 m4[4];
        #pragma unroll
        for (int n2 = 0; n2 < 4; ++n2)
            m4[n2] = *(const float4*)(mk + kbase + n2 * 16 + quad * 4);

        // K A-frags [m=key][k=d], V A-frags [m=d][k=key]
        short8 ka[4][2];
        #pragma unroll
        for (int n2 = 0; n2 < 4; ++n2) {
            ka[n2][0] = *(const short8*)&ksh[cur][(n2 * 16 + l15) * 72 + quad * 8];
            ka[n2][1] = *(const short8*)&ksh[cur][(n2 * 16 + l15) * 72 + 32 + quad * 8];
        }
        short8 vf[2][4];
        #pragma unroll
        for (int dt = 0; dt < 4; ++dt) {
            vf[0][dt] = *(const short8*)&vsh[cur][(dt * 16 + l15) * 72 + quad * 8];
            vf[1][dt] = *(const short8*)&vsh[cur][(dt * 16 + l15) * 72 + 32 + quad * 8];
        }

        #pragma unroll
        for (int g = 0; g < 2; ++g) {
            floatx4 st[4];
            #pragma unroll
            for (int n2 = 0; n2 < 4; ++n2) {
                floatx4 a = {0.f, 0.f, 0.f, 0.f};
                a = __builtin_amdgcn_mfma_f32_16x16x32_bf16(ka[n2][1], qa[g][1], a, 0, 0, 0);
                a = __builtin_amdgcn_mfma_f32_16x16x32_bf16(ka[n2][0], qa[g][0], a, 0, 0, 0);
                st[n2] = a;
            }
            const int prow = (w * 32 + g * 16 + l15) * 72;
            float psum = 0.f;
            #pragma unroll
            for (int n2 = 0; n2 < 4; ++n2) {
                float p0 = m4[n2].x * __builtin_amdgcn_exp2f(st[n2][0]);
                float p1 = m4[n2].y * __builtin_amdgcn_exp2f(st[n2][1]);
                float p2 = m4[n2].z * __builtin_amdgcn_exp2f(st[n2][2]);
                float p3 = m4[n2].w * __builtin_amdgcn_exp2f(st[n2][3]);
                psum += (p0 + p1) + (p2 + p3);
                *(int2*)&psh[prow + n2 * 16 + quad * 4] =
                    make_int2(f2bf_pk(p0, p1), f2bf_pk(p2, p3));
            }
            l_lane[g] += psum;
            // O^T += V^T·P^T (same-wave psh write->read; ds ordering suffices)
            #pragma unroll
            for (int kt = 0; kt < 2; ++kt) {
                short8 pa = *(const short8*)&psh[prow + kt * 32 + quad * 8];
                #pragma unroll
                for (int dt = 0; dt < 4; ++dt)
                    o_acc[g][dt] = __builtin_amdgcn_mfma_f32_16x16x32_bf16(vf[kt][dt], pa, o_acc[g][dt], 0, 0, 0);
            }
        }

        // project next chunk into the other buffer
        if (t < 15) {
            short8 wf[4][4];
            load_wf(wf);
            proj_mfma_write(xf, wf, cur ^ 1);
        }
        __syncthreads();
    }

    // epilogue: O^T layout => q=l15, d=dt*16+quad*4+i; float4 stores
    #pragma unroll
    for (int g = 0; g < 2; ++g) {
        float ls = l_lane[g];
        ls += __shfl_xor(ls, 16);
        ls += __shfl_xor(ls, 32);
        const float linv = 1.0f / ls;
        const int qr = qhalf * 256 + w * 32 + g * 16 + l15;
        float* orow = out + ((size_t)b * NQ_ + qr) * HD_ + h * D_;
        #pragma unroll
        for (int dt = 0; dt < 4; ++dt) {
            float4 v = make_float4(o_acc[g][dt][0] * linv, o_acc[g][dt][1] * linv,
                                   o_acc[g][dt][2] * linv, o_acc[g][dt][3] * linv);
            *(float4*)(orow + dt * 16 + quad * 4) = v;
        }
    }
}

extern "C" void kernel_launch(void* const* d_in, const int* in_sizes, int n_in,
                              void* d_out, int out_size, void* d_ws, size_t ws_size,
                              hipStream_t stream) {
    const float* query = (const float*)d_in[0];
    const float* key   = (const float*)d_in[1];
    const float* cmask = (const float*)d_in[2];
    const float* Wq    = (const float*)d_in[3];
    const float* bq    = (const float*)d_in[4];
    const float* Wk    = (const float*)d_in[5];
    // const float* bk = d_in[6], Wv = d_in[7], bv = d_in[8]
    const float* bk    = (const float*)d_in[6];
    const float* Wv    = (const float*)d_in[7];
    const float* bv    = (const float*)d_in[8];
    float* out = (float*)d_out;

    char* ws = (char*)d_ws;
    short* wqt = (short*)(ws);                    // 128 KB each (512*128 bf16)
    short* wkt = (short*)(ws + 131072);
    short* wvt = (short*)(ws + 131072 * 2);
    float* bqs = (float*)(ws + 131072 * 3);       // 2 KB

    const float qscale = 0.125f * 1.44269504f;    // 1/sqrt(64) * log2(e)
    prep_kernel<<<dim3(771), dim3(256), 0, stream>>>(
        Wq, Wk, Wv, wqt, wkt, wvt, bq, bqs, qscale);

    fused_kernel<<<dim3(256), dim3(512), 0, stream>>>(
        query, key, cmask, wqt, wkt, wvt, bqs, bk, bv, out);
}